// Round 1
// baseline (5068.450 us; speedup 1.0000x reference)
//
#include <hip/hip_runtime.h>
#include <math.h>

// Problem dims
#define NB 128
#define NN 36
#define NFEAT 2048
#define NMID 517
#define NHID 128
#define NOUT 1024
#define ROWS (NB*NN)          // 4608

__device__ __forceinline__ float sigf(float x){ return 1.f/(1.f+expf(-x)); }

// ---------------------------------------------------------------------------
// Kernel 1: per-batch box max + normalize, fill featsT rows 0..4.
// featsT layout: (B, N, MID) row-major: featsT[(b*36+n)*517 + m]
// ---------------------------------------------------------------------------
__global__ __launch_bounds__(64) void fill_small(const float* __restrict__ boxes,
                                                 const float* __restrict__ att,
                                                 float* __restrict__ feats)
{
    int b = blockIdx.x, tid = threadIdx.x;
    float mx = -1e30f;
    for (int idx = tid; idx < 4*NN; idx += 64) mx = fmaxf(mx, boxes[b*4*NN + idx]);
    for (int off = 32; off > 0; off >>= 1) mx = fmaxf(mx, __shfl_down(mx, off));
    mx = __shfl(mx, 0);
    float inv = 1.f / mx;
    for (int idx = tid; idx < 4*NN; idx += 64) {
        int r = idx / NN, n = idx - r*NN;
        feats[(size_t)(b*NN+n)*NMID + r] = boxes[b*4*NN + idx] * inv;
    }
    if (tid < NN) feats[(size_t)(b*NN+tid)*NMID + 4] = att[b*NN + tid];
}

// ---------------------------------------------------------------------------
// Generic fp32 GEMM:  C[m,n] = sum_k A[m,k]*B[n,k] + bias[n]
// A: M x K (lda), B: N x K (ldb), C: ldc (may be offset/strided into a larger
// buffer). M % 128 == 0, N % 128 == 0 required; K arbitrary (tail-guarded).
// 128x128 tile, BK=16, 256 threads, 8x8 per-thread micro-tile.
// ---------------------------------------------------------------------------
#define GBM 128
#define GBN 128
#define GBK 16

__global__ __launch_bounds__(256) void gemm_bt(
    const float* __restrict__ A, const float* __restrict__ Bm,
    const float* __restrict__ bias, float* __restrict__ C,
    int M, int N, int K, int lda, int ldb, int ldc)
{
    __shared__ float As[GBK][GBM+4];
    __shared__ float Bs[GBK][GBN+4];
    int n0 = blockIdx.x * GBN, m0 = blockIdx.y * GBM;
    int tid = threadIdx.x;
    int kk = tid & 15, rs = tid >> 4;      // load mapping
    int tx = tid & 15, ty = tid >> 4;      // compute mapping
    float acc[8][8] = {};
    for (int k0 = 0; k0 < K; k0 += GBK) {
        bool kin = (k0 + kk) < K;
        #pragma unroll
        for (int r = rs; r < GBM; r += 16)
            As[kk][r] = kin ? A[(size_t)(m0+r)*lda + k0 + kk] : 0.f;
        #pragma unroll
        for (int r = rs; r < GBN; r += 16)
            Bs[kk][r] = kin ? Bm[(size_t)(n0+r)*ldb + k0 + kk] : 0.f;
        __syncthreads();
        #pragma unroll
        for (int k = 0; k < GBK; ++k) {
            float a[8], bb[8];
            #pragma unroll
            for (int i = 0; i < 8; ++i) a[i] = As[k][ty*8+i];
            #pragma unroll
            for (int j = 0; j < 8; ++j) bb[j] = Bs[k][tx*8+j];
            #pragma unroll
            for (int i = 0; i < 8; ++i)
                #pragma unroll
                for (int j = 0; j < 8; ++j)
                    acc[i][j] += a[i]*bb[j];
        }
        __syncthreads();
    }
    #pragma unroll
    for (int i = 0; i < 8; ++i) {
        int m = m0 + ty*8 + i;
        #pragma unroll
        for (int j = 0; j < 8; ++j) {
            int n = n0 + tx*8 + j;
            float v = acc[i][j];
            if (bias) v += bias[n];
            C[(size_t)m*ldc + n] = v;
        }
    }
}

// ---------------------------------------------------------------------------
// Kernel 3: per-batch block. Builds out = w2 . relu(hx_i + hy_j) (b2 cancels
// in C = out - out^T), runs 3 assignment iterations, final A row-softmax
// (pre-multiplied by sigmoid(att)), then x -> xseq[(t=i)][b][c].
// hx has skew_b1 folded in as GEMM bias.
// hx/hy layout: (4608, 128): row b*36+i, col h.
// ---------------------------------------------------------------------------
__global__ __launch_bounds__(256) void assign_x(
    const float* __restrict__ feats, const float* __restrict__ hx,
    const float* __restrict__ hy, const float* __restrict__ att,
    const float* __restrict__ w2, const float* __restrict__ lr,
    float* __restrict__ xseq)
{
    __shared__ float s_hx[NN*NHID], s_hy[NN*NHID];
    __shared__ float s_out[NN*NN], s_C[NN*NN], s_logits[NN*NN], s_P[NN*NN];
    __shared__ float s_sg[NN], s_w2[NHID];
    int b = blockIdx.x, tid = threadIdx.x;
    for (int i = tid; i < NN*NHID; i += 256) {
        s_hx[i] = hx[(size_t)b*NN*NHID + i];
        s_hy[i] = hy[(size_t)b*NN*NHID + i];
    }
    if (tid < NHID) s_w2[tid] = w2[tid];
    if (tid < NN)   s_sg[tid] = sigf(att[b*NN + tid]);
    float lr_abs = fabsf(lr[0]);
    __syncthreads();
    // out[i][j] = sum_h w2[h] * relu(hx[i][h] + hy[j][h])   (b1 already in hx)
    for (int idx = tid; idx < NN*NN; idx += 256) {
        int i = idx / NN, j = idx - i*NN;
        const float* px = &s_hx[i*NHID];
        const float* py = &s_hy[j*NHID];
        float s = 0.f;
        #pragma unroll 8
        for (int h = 0; h < NHID; ++h) s += s_w2[h] * fmaxf(px[h] + py[h], 0.f);
        s_out[idx] = s;
        s_logits[idx] = 0.f;
    }
    __syncthreads();
    for (int idx = tid; idx < NN*NN; idx += 256) {
        int i = idx / NN, j = idx - i*NN;
        s_C[idx] = s_out[idx] - s_out[j*NN + i];
    }
    __syncthreads();
    // 3 assignment iterations
    for (int it = 0; it < 3; ++it) {
        if (tid < NN) {     // row softmax -> P
            int i = tid;
            float mx = -1e30f;
            for (int l = 0; l < NN; ++l) mx = fmaxf(mx, s_logits[i*NN+l]);
            float sum = 0.f;
            for (int l = 0; l < NN; ++l) { float e = expf(s_logits[i*NN+l]-mx); s_P[i*NN+l] = e; sum += e; }
            float inv = 1.f/sum;
            for (int l = 0; l < NN; ++l) s_P[i*NN+l] *= inv;
        }
        __syncthreads();
        if (tid < NN) {     // per-column: D = S - 2*cum + P (in place)
            int l = tid;
            float S = 0.f;
            for (int i = 0; i < NN; ++i) S += s_P[i*NN+l];
            float cum = 0.f;
            for (int i = 0; i < NN; ++i) {
                float p = s_P[i*NN+l];
                cum += p;
                s_P[i*NN+l] = S - 2.f*cum + p;
            }
        }
        __syncthreads();
        // logits[i][j] -= lr * sum_l D[i][l]*C[j][l]
        for (int idx = tid; idx < NN*NN; idx += 256) {
            int i = idx / NN, j = idx - i*NN;
            float g = 0.f;
            #pragma unroll
            for (int l = 0; l < NN; ++l) g += s_P[i*NN+l] * s_C[j*NN+l];
            s_logits[idx] -= lr_abs * g;
        }
        __syncthreads();
    }
    // final A = softmax(logits) rows, pre-scaled by sigmoid(att[l])
    if (tid < NN) {
        int i = tid;
        float mx = -1e30f;
        for (int l = 0; l < NN; ++l) mx = fmaxf(mx, s_logits[i*NN+l]);
        float sum = 0.f;
        for (int l = 0; l < NN; ++l) { float e = expf(s_logits[i*NN+l]-mx); s_P[i*NN+l] = e; sum += e; }
        float inv = 1.f/sum;
        for (int l = 0; l < NN; ++l) s_P[i*NN+l] *= inv * s_sg[l];
    }
    __syncthreads();
    // x[b,c,i] = sum_l feats[b,l,c]*sg[l]*A[i,l]  -> xseq[i][b][c]
    const float* fb = feats + (size_t)b*NN*NMID;
    for (int idx = tid; idx < NN*NMID; idx += 256) {
        int i = idx / NMID, cpos = idx - i*NMID;
        float s = 0.f;
        #pragma unroll
        for (int l = 0; l < NN; ++l) s += fb[l*NMID + cpos] * s_P[i*NN + l];
        xseq[((size_t)i*NB + b)*NMID + cpos] = s;
    }
}

// ---------------------------------------------------------------------------
// LSTM step: gates[b, g*1024+u] = xw_t[b, g*1024+u] (has b_ih) + b_hh + h.w_hh^T
// Tile: 32 batches x 16 units x 4 gates per block; 256 threads, each owns
// 2 batches x 1 unit x 4 gates. h ping-pong across launches; c in-place.
// ---------------------------------------------------------------------------
__global__ __launch_bounds__(256) void lstm_step(
    const float* __restrict__ xw_t, const float* __restrict__ w_hh,
    const float* __restrict__ b_hh, const float* __restrict__ h_in,
    float* __restrict__ h_out, float* __restrict__ c)
{
    __shared__ float h_s[32][65];
    __shared__ float w_s[64][65];
    int u0 = blockIdx.x * 16, b0 = blockIdx.y * 32;
    int tid = threadIdx.x;
    int u_l = tid & 15, b_l = tid >> 4;
    int kkl = tid & 63, rl = tid >> 6;
    float acc[2][4] = {};
    for (int kt = 0; kt < NOUT; kt += 64) {
        #pragma unroll
        for (int r = rl; r < 32; r += 4)
            h_s[r][kkl] = h_in[(size_t)(b0+r)*NOUT + kt + kkl];
        #pragma unroll
        for (int r = rl; r < 64; r += 4) {
            int g = r >> 4, urel = r & 15;
            w_s[r][kkl] = w_hh[(size_t)(g*NOUT + u0 + urel)*NOUT + kt + kkl];
        }
        __syncthreads();
        #pragma unroll
        for (int k = 0; k < 64; ++k) {
            float a0 = h_s[b_l][k], a1 = h_s[b_l+16][k];
            #pragma unroll
            for (int g = 0; g < 4; ++g) {
                float w = w_s[g*16 + u_l][k];
                acc[0][g] += a0 * w;
                acc[1][g] += a1 * w;
            }
        }
        __syncthreads();
    }
    #pragma unroll
    for (int p = 0; p < 2; ++p) {
        int b = b0 + b_l + 16*p;
        int u = u0 + u_l;
        const float* xr = xw_t + (size_t)b*4*NOUT;
        float g0 = xr[u]          + b_hh[u]          + acc[p][0];
        float g1 = xr[NOUT+u]     + b_hh[NOUT+u]     + acc[p][1];
        float g2 = xr[2*NOUT+u]   + b_hh[2*NOUT+u]   + acc[p][2];
        float g3 = xr[3*NOUT+u]   + b_hh[3*NOUT+u]   + acc[p][3];
        float ig = sigf(g0), fg = sigf(g1), gg = tanhf(g2), og = sigf(g3);
        float cc = fg * c[(size_t)b*NOUT + u] + ig * gg;
        c[(size_t)b*NOUT + u] = cc;
        h_out[(size_t)b*NOUT + u] = og * tanhf(cc);
    }
}

__global__ __launch_bounds__(256) void init_state(float* __restrict__ h0, float* __restrict__ c)
{
    int i = blockIdx.x*256 + threadIdx.x;
    h0[i] = 0.f; c[i] = 0.f;
}

__global__ __launch_bounds__(256) void copy_out(const float* __restrict__ c, float* __restrict__ out)
{
    int i = blockIdx.x*256 + threadIdx.x;
    out[i] = c[i];
}

// ---------------------------------------------------------------------------
extern "C" void kernel_launch(void* const* d_in, const int* in_sizes, int n_in,
                              void* d_out, int out_size, void* d_ws, size_t ws_size,
                              hipStream_t stream) {
    (void)in_sizes; (void)n_in; (void)out_size; (void)ws_size;
    const float* boxes     = (const float*)d_in[0];
    const float* attention = (const float*)d_in[1];
    const float* features  = (const float*)d_in[2];
    const float* conv_w    = (const float*)d_in[3];
    const float* conv_b    = (const float*)d_in[4];
    const float* skew_wx   = (const float*)d_in[5];
    const float* skew_wy   = (const float*)d_in[6];
    const float* skew_b1   = (const float*)d_in[7];
    const float* skew_w2   = (const float*)d_in[8];
    // d_in[9] = skew_b2: cancels in C = out - out^T, unused
    const float* w_ih      = (const float*)d_in[10];
    const float* w_hh      = (const float*)d_in[11];
    const float* b_ih      = (const float*)d_in[12];
    const float* b_hh      = (const float*)d_in[13];
    const float* lr        = (const float*)d_in[14];

    // workspace layout (all 256B-aligned)
    char* ws = (char*)d_ws;
    float* feats = (float*)(ws);                       // 4608 x 517   (9,529,344 B)
    float* hx    = (float*)(ws + 9529344);             // 4608 x 128   (2,359,296 B)
    float* hy    = (float*)(ws + 11888640);            // 4608 x 128
    float* xseq  = (float*)(ws + 14247936);            // 36 x 128 x 517
    float* xw    = (float*)(ws + 23777280);            // 4608 x 4096  (75,497,472 B)
    float* h0    = (float*)(ws + 99274752);            // 128 x 1024
    float* h1    = (float*)(ws + 99799040);            // 128 x 1024
    float* cst   = (float*)(ws + 100323328);           // 128 x 1024

    fill_small<<<NB, 64, 0, stream>>>(boxes, attention, feats);
    // conv: feats[:, :, 5:517] = features(4608x2048) . conv_w(512x2048)^T + conv_b
    gemm_bt<<<dim3(4, 36), 256, 0, stream>>>(features, conv_w, conv_b, feats + 5,
                                             ROWS, 512, NFEAT, NFEAT, NFEAT, NMID);
    // hx = feats . skew_wx^T + skew_b1 ; hy = feats . skew_wy^T
    gemm_bt<<<dim3(1, 36), 256, 0, stream>>>(feats, skew_wx, skew_b1, hx,
                                             ROWS, NHID, NMID, NMID, NMID, NHID);
    gemm_bt<<<dim3(1, 36), 256, 0, stream>>>(feats, skew_wy, nullptr, hy,
                                             ROWS, NHID, NMID, NMID, NMID, NHID);
    assign_x<<<NB, 256, 0, stream>>>(feats, hx, hy, attention, skew_w2, lr, xseq);
    // xw = xseq(4608x517) . w_ih(4096x517)^T + b_ih
    gemm_bt<<<dim3(32, 36), 256, 0, stream>>>(xseq, w_ih, b_ih, xw,
                                              ROWS, 4*NOUT, NMID, NMID, NMID, 4*NOUT);
    init_state<<<(NB*NOUT)/256, 256, 0, stream>>>(h0, cst);
    float* hbuf[2] = {h0, h1};
    for (int t = 0; t < NN; ++t) {
        lstm_step<<<dim3(64, 4), 256, 0, stream>>>(xw + (size_t)t*NB*4*NOUT, w_hh, b_hh,
                                                   hbuf[t & 1], hbuf[(t+1) & 1], cst);
    }
    copy_out<<<(NB*NOUT)/256, 256, 0, stream>>>(cst, (float*)d_out);
}

// Round 2
// 1452.814 us; speedup vs baseline: 3.4887x; 3.4887x over previous
//
#include <hip/hip_runtime.h>
#include <math.h>

// Problem dims
#define NB 128
#define NN 36
#define NFEAT 2048
#define NMID 517
#define KP 544            // padded K (multiple of 32) for MID-dim GEMMs
#define NHID 128
#define NOUT 1024
#define ROWS (NB*NN)      // 4608

typedef __bf16 bf16x8 __attribute__((ext_vector_type(8)));
typedef float  f32x4  __attribute__((ext_vector_type(4)));

__device__ __forceinline__ float sigf(float x){ return 1.f/(1.f+expf(-x)); }
__device__ __forceinline__ unsigned short f2bf(float x){
    unsigned u = __float_as_uint(x);
    return (unsigned short)((u + 0x7FFFu + ((u>>16)&1u)) >> 16);
}
__device__ __forceinline__ float bf2f(unsigned short b){
    return __uint_as_float(((unsigned)b) << 16);
}

// ---------------------------------------------------------------------------
// per-batch box max + normalize, fill feats fp32 cols 0..4
// feats layout: (B*N, 517) row-major
// ---------------------------------------------------------------------------
__global__ __launch_bounds__(64) void fill_small(const float* __restrict__ boxes,
                                                 const float* __restrict__ att,
                                                 float* __restrict__ feats)
{
    int b = blockIdx.x, tid = threadIdx.x;
    float mx = -1e30f;
    for (int idx = tid; idx < 4*NN; idx += 64) mx = fmaxf(mx, boxes[b*4*NN + idx]);
    for (int off = 32; off > 0; off >>= 1) mx = fmaxf(mx, __shfl_down(mx, off));
    mx = __shfl(mx, 0);
    float inv = 1.f / mx;
    for (int idx = tid; idx < 4*NN; idx += 64) {
        int r = idx / NN, n = idx - r*NN;
        feats[(size_t)(b*NN+n)*NMID + r] = boxes[b*4*NN + idx] * inv;
    }
    if (tid < NN) feats[(size_t)(b*NN+tid)*NMID + 4] = att[b*NN + tid];
}

// ---------------------------------------------------------------------------
// cast / reorder prep kernels
// ---------------------------------------------------------------------------
__global__ __launch_bounds__(256) void cast_bf16(const float* __restrict__ s,
                                                 unsigned short* __restrict__ d, int n)
{
    int stride = gridDim.x*256;
    for (int i = blockIdx.x*256 + threadIdx.x; i < n; i += stride) d[i] = f2bf(s[i]);
}

// (rows x sld) fp32 -> (rows x KP) bf16, zero-padded cols sld..KP-1
__global__ __launch_bounds__(256) void cast_pad(const float* __restrict__ s,
                                                unsigned short* __restrict__ d,
                                                int rows, int sld)
{
    int n = rows*KP, stride = gridDim.x*256;
    for (int i = blockIdx.x*256 + threadIdx.x; i < n; i += stride) {
        int r = i / KP, k = i - r*KP;
        d[i] = (k < sld) ? f2bf(s[(size_t)r*sld + k]) : (unsigned short)0;
    }
}

// wxy bf16 (256 x KP): rows 0..127 = skew_wx, 128..255 = skew_wy; bias (256)
__global__ __launch_bounds__(256) void build_wxy(const float* __restrict__ wx,
                                                 const float* __restrict__ wy,
                                                 const float* __restrict__ b1,
                                                 unsigned short* __restrict__ d,
                                                 float* __restrict__ hbias)
{
    int n = 256*KP, stride = gridDim.x*256;
    for (int i = blockIdx.x*256 + threadIdx.x; i < n; i += stride) {
        int r = i / KP, k = i - r*KP;
        float v = 0.f;
        if (k < NMID) v = (r < NHID) ? wx[(size_t)r*NMID+k] : wy[(size_t)(r-NHID)*NMID+k];
        d[i] = f2bf(v);
    }
    for (int i = blockIdx.x*256 + threadIdx.x; i < 256; i += stride)
        hbias[i] = (i < NHID) ? b1[i] : 0.f;
}

// w_ih (4096 x 517) -> interleaved row u*4+g, padded to KP, bf16
__global__ __launch_bounds__(256) void prep_wih(const float* __restrict__ w,
                                                unsigned short* __restrict__ d)
{
    int n = 4*NOUT*KP, stride = gridDim.x*256;
    for (int i = blockIdx.x*256 + threadIdx.x; i < n; i += stride) {
        int row = i / KP, k = i - row*KP;
        int u = row >> 2, g = row & 3;
        d[i] = (k < NMID) ? f2bf(w[(size_t)(g*NOUT+u)*NMID + k]) : (unsigned short)0;
    }
}

// w_hh (4096 x 1024) -> interleaved row u*4+g, bf16
__global__ __launch_bounds__(256) void prep_whh(const float* __restrict__ w,
                                                unsigned short* __restrict__ d)
{
    int n = 4*NOUT*NOUT, stride = gridDim.x*256;
    for (int i = blockIdx.x*256 + threadIdx.x; i < n; i += stride) {
        int row = i >> 10, k = i & 1023;
        int u = row >> 2, g = row & 3;
        d[i] = f2bf(w[(size_t)(g*NOUT+u)*NOUT + k]);
    }
}

// combined interleaved bias (b_ih+b_hh), zero h0 (bf16) and c (fp32)
__global__ __launch_bounds__(256) void prep_misc(const float* __restrict__ b_ih,
                                                 const float* __restrict__ b_hh,
                                                 float* __restrict__ comb,
                                                 unsigned short* __restrict__ h0,
                                                 float* __restrict__ c)
{
    int stride = gridDim.x*256;
    for (int i = blockIdx.x*256 + threadIdx.x; i < 4*NOUT; i += stride) {
        int u = i >> 2, g = i & 3;
        comb[i] = b_ih[g*NOUT+u] + b_hh[g*NOUT+u];
    }
    for (int i = blockIdx.x*256 + threadIdx.x; i < NB*NOUT; i += stride) {
        h0[i] = 0; c[i] = 0.f;
    }
}

// ---------------------------------------------------------------------------
// bf16 MFMA GEMM: C[m,n] = sum_k A[m,k]*B[n,k] + bias[n]
// A (M x K) bf16 row-major, B (N x K) bf16 row-major, C fp32 or bf16 (obf).
// Block tile 128x64, 256 thr = 4 waves (2x2), wave tile 64x32.
// LDS fragment-major: chunk (mtile, q*16+m) of 16B -> lane-sequential reads.
// M = gridDim.y*128, N = gridDim.x*64, K % 32 == 0.
// ---------------------------------------------------------------------------
__global__ __launch_bounds__(256) void gemm_mfma(
    const unsigned short* __restrict__ A, const unsigned short* __restrict__ B,
    const float* __restrict__ bias, void* __restrict__ Cp,
    int K, int lda, int ldb, int ldc, int obf)
{
    __shared__ __align__(16) char As[8192];   // 8 mtiles x 1KB
    __shared__ __align__(16) char Bs[4096];   // 4 ntiles x 1KB
    int m0 = blockIdx.y * 128, n0 = blockIdx.x * 64;
    int tid = threadIdx.x;
    int lane = tid & 63, wave = tid >> 6;
    int wm = wave >> 1, wn = wave & 1;
    f32x4 acc[4][2];
    #pragma unroll
    for (int i = 0; i < 4; ++i)
        #pragma unroll
        for (int j = 0; j < 2; ++j) acc[i][j] = (f32x4){0.f,0.f,0.f,0.f};

    for (int k0 = 0; k0 < K; k0 += 32) {
        #pragma unroll
        for (int cc = tid; cc < 512; cc += 256) {      // A: 128 rows x 4 quads
            int r = cc >> 2, q = cc & 3;
            uint4 v = *(const uint4*)(A + (size_t)(m0+r)*lda + k0 + q*8);
            *(uint4*)(As + ((r>>4)<<10) + (q<<8) + ((r&15)<<4)) = v;
        }
        {                                              // B: 64 rows x 4 quads
            int r = tid >> 2, q = tid & 3;
            uint4 v = *(const uint4*)(B + (size_t)(n0+r)*ldb + k0 + q*8);
            *(uint4*)(Bs + ((r>>4)<<10) + (q<<8) + ((r&15)<<4)) = v;
        }
        __syncthreads();
        bf16x8 af[4], bfr[2];
        #pragma unroll
        for (int i = 0; i < 4; ++i) af[i]  = *(bf16x8*)(As + ((wm*4+i)<<10) + (lane<<4));
        #pragma unroll
        for (int j = 0; j < 2; ++j) bfr[j] = *(bf16x8*)(Bs + ((wn*2+j)<<10) + (lane<<4));
        #pragma unroll
        for (int i = 0; i < 4; ++i)
            #pragma unroll
            for (int j = 0; j < 2; ++j)
                acc[i][j] = __builtin_amdgcn_mfma_f32_16x16x32_bf16(af[i], bfr[j], acc[i][j], 0, 0, 0);
        __syncthreads();
    }
    int colf = lane & 15, rowq = lane >> 4;
    #pragma unroll
    for (int j = 0; j < 2; ++j) {
        int col = n0 + (wn*2+j)*16 + colf;
        float bv = bias ? bias[col] : 0.f;
        #pragma unroll
        for (int i = 0; i < 4; ++i) {
            #pragma unroll
            for (int reg = 0; reg < 4; ++reg) {
                int row = m0 + (wm*4+i)*16 + rowq*4 + reg;
                float v = acc[i][j][reg] + bv;
                if (obf) ((unsigned short*)Cp)[(size_t)row*ldc + col] = f2bf(v);
                else     ((float*)Cp)[(size_t)row*ldc + col] = v;
            }
        }
    }
}

// ---------------------------------------------------------------------------
// per-batch: out = w2.relu(hx_i+hy_j) (b2 cancels), 3 assignment iters,
// final A row-softmax pre-scaled by sigmoid(att), x -> xseq (bf16, padded).
// hxy: (4608 x 256) fp32, cols 0..127 = hx (b1 folded), 128..255 = hy.
// ---------------------------------------------------------------------------
__global__ __launch_bounds__(256) void assign_x(
    const float* __restrict__ feats, const float* __restrict__ hxy,
    const float* __restrict__ att, const float* __restrict__ w2,
    const float* __restrict__ lr, unsigned short* __restrict__ xseq)
{
    __shared__ float s_hx[NN*NHID], s_hy[NN*NHID];
    __shared__ float s_out[NN*NN], s_C[NN*NN], s_logits[NN*NN], s_P[NN*NN];
    __shared__ float s_sg[NN], s_w2[NHID];
    int b = blockIdx.x, tid = threadIdx.x;
    for (int i = tid; i < NN*NHID; i += 256) {
        int n = i >> 7, h = i & 127;
        s_hx[i] = hxy[(size_t)(b*NN+n)*256 + h];
        s_hy[i] = hxy[(size_t)(b*NN+n)*256 + 128 + h];
    }
    if (tid < NHID) s_w2[tid] = w2[tid];
    if (tid < NN)   s_sg[tid] = sigf(att[b*NN + tid]);
    float lr_abs = fabsf(lr[0]);
    __syncthreads();
    for (int idx = tid; idx < NN*NN; idx += 256) {
        int i = idx / NN, j = idx - i*NN;
        const float* px = &s_hx[i*NHID];
        const float* py = &s_hy[j*NHID];
        float s = 0.f;
        #pragma unroll 8
        for (int h = 0; h < NHID; ++h) s += s_w2[h] * fmaxf(px[h] + py[h], 0.f);
        s_out[idx] = s;
        s_logits[idx] = 0.f;
    }
    __syncthreads();
    for (int idx = tid; idx < NN*NN; idx += 256) {
        int i = idx / NN, j = idx - i*NN;
        s_C[idx] = s_out[idx] - s_out[j*NN + i];
    }
    __syncthreads();
    for (int it = 0; it < 3; ++it) {
        if (tid < NN) {
            int i = tid;
            float mx = -1e30f;
            for (int l = 0; l < NN; ++l) mx = fmaxf(mx, s_logits[i*NN+l]);
            float sum = 0.f;
            for (int l = 0; l < NN; ++l) { float e = expf(s_logits[i*NN+l]-mx); s_P[i*NN+l] = e; sum += e; }
            float inv = 1.f/sum;
            for (int l = 0; l < NN; ++l) s_P[i*NN+l] *= inv;
        }
        __syncthreads();
        if (tid < NN) {
            int l = tid;
            float S = 0.f;
            for (int i = 0; i < NN; ++i) S += s_P[i*NN+l];
            float cum = 0.f;
            for (int i = 0; i < NN; ++i) {
                float p = s_P[i*NN+l];
                cum += p;
                s_P[i*NN+l] = S - 2.f*cum + p;
            }
        }
        __syncthreads();
        for (int idx = tid; idx < NN*NN; idx += 256) {
            int i = idx / NN, j = idx - i*NN;
            float g = 0.f;
            #pragma unroll
            for (int l = 0; l < NN; ++l) g += s_P[i*NN+l] * s_C[j*NN+l];
            s_logits[idx] -= lr_abs * g;
        }
        __syncthreads();
    }
    if (tid < NN) {
        int i = tid;
        float mx = -1e30f;
        for (int l = 0; l < NN; ++l) mx = fmaxf(mx, s_logits[i*NN+l]);
        float sum = 0.f;
        for (int l = 0; l < NN; ++l) { float e = expf(s_logits[i*NN+l]-mx); s_P[i*NN+l] = e; sum += e; }
        float inv = 1.f/sum;
        for (int l = 0; l < NN; ++l) s_P[i*NN+l] *= inv * s_sg[l];
    }
    __syncthreads();
    const float* fb = feats + (size_t)b*NN*NMID;
    for (int idx = tid; idx < NN*NMID; idx += 256) {
        int i = idx / NMID, cpos = idx - i*NMID;
        float s = 0.f;
        #pragma unroll
        for (int l = 0; l < NN; ++l) s += fb[l*NMID + cpos] * s_P[i*NN + l];
        xseq[((size_t)i*NB + b)*KP + cpos] = f2bf(s);
    }
    for (int idx = tid; idx < NN*(KP-NMID); idx += 256) {   // zero pad cols
        int i = idx / (KP-NMID), c2 = NMID + idx - i*(KP-NMID);
        xseq[((size_t)i*NB + b)*KP + c2] = 0;
    }
}

// ---------------------------------------------------------------------------
// LSTM step, MFMA: gates(128 x 64-slice) = h(128x1024 bf16) . whh_il^T,
// + xw (bf16, bias folded), nonlinearity, c fp32 in-place, h_out bf16.
// Columns are unit-major interleaved: n = u*4+g. Grid 64 blocks.
// ---------------------------------------------------------------------------
__global__ __launch_bounds__(256) void lstm_step(
    const unsigned short* __restrict__ h_in, const unsigned short* __restrict__ whh,
    const unsigned short* __restrict__ xw_t, float* __restrict__ c,
    unsigned short* __restrict__ h_out)
{
    __shared__ __align__(16) char As[8192];
    __shared__ __align__(16) char Bs[4096];
    __shared__ float gates[128][68];   // pad 68: write conflicts 2-way (free)
    int tid = threadIdx.x;
    int lane = tid & 63, wave = tid >> 6;
    int wm = wave >> 1, wn = wave & 1;
    int n0 = blockIdx.x * 64;
    f32x4 acc[4][2];
    #pragma unroll
    for (int i = 0; i < 4; ++i)
        #pragma unroll
        for (int j = 0; j < 2; ++j) acc[i][j] = (f32x4){0.f,0.f,0.f,0.f};

    for (int k0 = 0; k0 < NOUT; k0 += 32) {
        #pragma unroll
        for (int cc = tid; cc < 512; cc += 256) {
            int r = cc >> 2, q = cc & 3;
            uint4 v = *(const uint4*)(h_in + (size_t)r*NOUT + k0 + q*8);
            *(uint4*)(As + ((r>>4)<<10) + (q<<8) + ((r&15)<<4)) = v;
        }
        {
            int r = tid >> 2, q = tid & 3;
            uint4 v = *(const uint4*)(whh + (size_t)(n0+r)*NOUT + k0 + q*8);
            *(uint4*)(Bs + ((r>>4)<<10) + (q<<8) + ((r&15)<<4)) = v;
        }
        __syncthreads();
        bf16x8 af[4], bfr[2];
        #pragma unroll
        for (int i = 0; i < 4; ++i) af[i]  = *(bf16x8*)(As + ((wm*4+i)<<10) + (lane<<4));
        #pragma unroll
        for (int j = 0; j < 2; ++j) bfr[j] = *(bf16x8*)(Bs + ((wn*2+j)<<10) + (lane<<4));
        #pragma unroll
        for (int i = 0; i < 4; ++i)
            #pragma unroll
            for (int j = 0; j < 2; ++j)
                acc[i][j] = __builtin_amdgcn_mfma_f32_16x16x32_bf16(af[i], bfr[j], acc[i][j], 0, 0, 0);
        __syncthreads();
    }
    int colf = lane & 15, rowq = lane >> 4;
    #pragma unroll
    for (int i = 0; i < 4; ++i)
        #pragma unroll
        for (int j = 0; j < 2; ++j)
            #pragma unroll
            for (int reg = 0; reg < 4; ++reg)
                gates[(wm*4+i)*16 + rowq*4 + reg][(wn*2+j)*16 + colf] = acc[i][j][reg];
    __syncthreads();
    int u0 = blockIdx.x * 16;
    #pragma unroll
    for (int p = 0; p < 8; ++p) {
        int idx = p*256 + tid;
        int ul = idx & 15, b = idx >> 4;
        float4 gl = *(const float4*)&gates[b][ul*4];
        const unsigned short* xr = xw_t + (size_t)b*4*NOUT + (size_t)(u0+ul)*4;
        float g0 = gl.x + bf2f(xr[0]);
        float g1 = gl.y + bf2f(xr[1]);
        float g2 = gl.z + bf2f(xr[2]);
        float g3 = gl.w + bf2f(xr[3]);
        float ig = sigf(g0), fg = sigf(g1), gg = tanhf(g2), og = sigf(g3);
        size_t o = (size_t)b*NOUT + u0 + ul;
        float cc = fg*c[o] + ig*gg;
        c[o] = cc;
        h_out[o] = f2bf(og*tanhf(cc));
    }
}

__global__ __launch_bounds__(256) void copy_out(const float* __restrict__ c, float* __restrict__ out)
{
    int i = blockIdx.x*256 + threadIdx.x;
    out[i] = c[i];
}

// ---------------------------------------------------------------------------
extern "C" void kernel_launch(void* const* d_in, const int* in_sizes, int n_in,
                              void* d_out, int out_size, void* d_ws, size_t ws_size,
                              hipStream_t stream) {
    (void)in_sizes; (void)n_in; (void)out_size; (void)ws_size;
    const float* boxes     = (const float*)d_in[0];
    const float* attention = (const float*)d_in[1];
    const float* features  = (const float*)d_in[2];
    const float* conv_w    = (const float*)d_in[3];
    const float* conv_b    = (const float*)d_in[4];
    const float* skew_wx   = (const float*)d_in[5];
    const float* skew_wy   = (const float*)d_in[6];
    const float* skew_b1   = (const float*)d_in[7];
    const float* skew_w2   = (const float*)d_in[8];
    // d_in[9] = skew_b2: cancels in C = out - out^T
    const float* w_ih      = (const float*)d_in[10];
    const float* w_hh      = (const float*)d_in[11];
    const float* b_ih      = (const float*)d_in[12];
    const float* b_hh      = (const float*)d_in[13];
    const float* lr        = (const float*)d_in[14];

    // workspace layout (bytes, all 256-aligned)
    char* ws = (char*)d_ws;
    float*          feats    = (float*)(ws);                      // 4608x517 f32   9,529,344
    float*          hxy      = (float*)(ws + 9529344);            // 4608x256 f32   4,718,592
    unsigned short* feats_bf = (unsigned short*)(ws + 14247936);  // 4608x544 bf16  5,013,504
    unsigned short* xseq_bf  = (unsigned short*)(ws + 19261440);  // 4608x544 bf16  5,013,504
    unsigned short* wih_il   = (unsigned short*)(ws + 24274944);  // 4096x544 bf16  4,456,448
    unsigned short* whh_il   = (unsigned short*)(ws + 28731392);  // 4096x1024 bf16 8,388,608
    unsigned short* wxy_bf   = (unsigned short*)(ws + 37120000);  // 256x544 bf16     278,528
    float*          comb_b   = (float*)(ws + 37398528);           // 4096 f32          16,384
    float*          hxy_b    = (float*)(ws + 37414912);           // 256 f32            1,024
    unsigned short* h0       = (unsigned short*)(ws + 37416192);  // 128x1024 bf16    262,144
    unsigned short* h1       = (unsigned short*)(ws + 37678336);  // 128x1024 bf16    262,144
    float*          cst      = (float*)(ws + 37940480);           // 128x1024 f32     524,288
    unsigned short* xw_bf    = (unsigned short*)(ws + 38464768);  // 4608x4096 bf16 37,748,736
    // features_bf / convw_bf overlap xw_bf region (dead before xw GEMM writes)
    unsigned short* features_bf = xw_bf;                          // 4608x2048 bf16 18,874,368
    unsigned short* convw_bf = (unsigned short*)(ws + 38464768 + 18874368); // 512x2048 bf16

    // prep
    fill_small<<<NB, 64, 0, stream>>>(boxes, attention, feats);
    cast_bf16<<<2048, 256, 0, stream>>>(features, features_bf, ROWS*NFEAT);
    cast_bf16<<<512, 256, 0, stream>>>(conv_w, convw_bf, 512*NFEAT);
    prep_wih<<<1024, 256, 0, stream>>>(w_ih, wih_il);
    prep_whh<<<2048, 256, 0, stream>>>(w_hh, whh_il);
    prep_misc<<<512, 256, 0, stream>>>(b_ih, b_hh, comb_b, h0, cst);
    build_wxy<<<128, 256, 0, stream>>>(skew_wx, skew_wy, skew_b1, wxy_bf, hxy_b);

    // conv: feats[:,5:517] = features . conv_w^T + conv_b
    gemm_mfma<<<dim3(8, 36), 256, 0, stream>>>(features_bf, convw_bf, conv_b,
                                               (void*)(feats + 5), NFEAT, NFEAT, NFEAT, NMID, 0);
    cast_pad<<<1024, 256, 0, stream>>>(feats, feats_bf, ROWS, NMID);
    // hxy = feats . [wx;wy]^T + [b1;0]
    gemm_mfma<<<dim3(4, 36), 256, 0, stream>>>(feats_bf, wxy_bf, hxy_b,
                                               (void*)hxy, KP, KP, KP, 256, 0);
    assign_x<<<NB, 256, 0, stream>>>(feats, hxy, attention, skew_w2, lr, xseq_bf);
    // xw = xseq . w_ih_il^T + (b_ih+b_hh)  -> bf16
    gemm_mfma<<<dim3(64, 36), 256, 0, stream>>>(xseq_bf, wih_il, comb_b,
                                                (void*)xw_bf, KP, KP, KP, 4*NOUT, 1);
    unsigned short* hbuf[2] = {h0, h1};
    for (int t = 0; t < NN; ++t) {
        lstm_step<<<64, 256, 0, stream>>>(hbuf[t & 1], whh_il,
                                          xw_bf + (size_t)t*NB*4*NOUT, cst, hbuf[(t+1) & 1]);
    }
    copy_out<<<(NB*NOUT)/256, 256, 0, stream>>>(cst, (float*)d_out);
}

// Round 3
// 919.499 us; speedup vs baseline: 5.5122x; 1.5800x over previous
//
#include <hip/hip_runtime.h>
#include <math.h>

// Problem dims
#define NB 128
#define NN 36
#define S36 37            // padded stride for 36x36 LDS arrays (bank-conflict-free)
#define NFEAT 2048
#define NMID 517
#define KP 544            // padded K (multiple of 32) for MID-dim GEMMs
#define NHID 128
#define NOUT 1024
#define ROWS (NB*NN)      // 4608

typedef __bf16 bf16x8 __attribute__((ext_vector_type(8)));
typedef float  f32x4  __attribute__((ext_vector_type(4)));

__device__ __forceinline__ float sigf(float x){ return 1.f/(1.f+expf(-x)); }
__device__ __forceinline__ unsigned short f2bf(float x){
    unsigned u = __float_as_uint(x);
    return (unsigned short)((u + 0x7FFFu + ((u>>16)&1u)) >> 16);
}
__device__ __forceinline__ float bf2f(unsigned short b){
    return __uint_as_float(((unsigned)b) << 16);
}

// ---------------------------------------------------------------------------
// per-batch box max + normalize, fill feats fp32 cols 0..4
// ---------------------------------------------------------------------------
__global__ __launch_bounds__(64) void fill_small(const float* __restrict__ boxes,
                                                 const float* __restrict__ att,
                                                 float* __restrict__ feats)
{
    int b = blockIdx.x, tid = threadIdx.x;
    float mx = -1e30f;
    for (int idx = tid; idx < 4*NN; idx += 64) mx = fmaxf(mx, boxes[b*4*NN + idx]);
    for (int off = 32; off > 0; off >>= 1) mx = fmaxf(mx, __shfl_down(mx, off));
    mx = __shfl(mx, 0);
    float inv = 1.f / mx;
    for (int idx = tid; idx < 4*NN; idx += 64) {
        int r = idx / NN, n = idx - r*NN;
        feats[(size_t)(b*NN+n)*NMID + r] = boxes[b*4*NN + idx] * inv;
    }
    if (tid < NN) feats[(size_t)(b*NN+tid)*NMID + 4] = att[b*NN + tid];
}

// ---------------------------------------------------------------------------
// cast / reorder prep kernels
// ---------------------------------------------------------------------------
__global__ __launch_bounds__(256) void cast_bf16(const float* __restrict__ s,
                                                 unsigned short* __restrict__ d, int n)
{
    int stride = gridDim.x*256;
    for (int i = blockIdx.x*256 + threadIdx.x; i < n; i += stride) d[i] = f2bf(s[i]);
}

// (rows x sld) fp32 -> (rows x KP) bf16, zero-padded cols sld..KP-1
__global__ __launch_bounds__(256) void cast_pad(const float* __restrict__ s,
                                                unsigned short* __restrict__ d,
                                                int rows, int sld)
{
    int n = rows*KP, stride = gridDim.x*256;
    for (int i = blockIdx.x*256 + threadIdx.x; i < n; i += stride) {
        int r = i / KP, k = i - r*KP;
        d[i] = (k < sld) ? f2bf(s[(size_t)r*sld + k]) : (unsigned short)0;
    }
}

// wxy bf16 (256 x KP): rows 0..127 = skew_wx, 128..255 = skew_wy; bias (256)
__global__ __launch_bounds__(256) void build_wxy(const float* __restrict__ wx,
                                                 const float* __restrict__ wy,
                                                 const float* __restrict__ b1,
                                                 unsigned short* __restrict__ d,
                                                 float* __restrict__ hbias)
{
    int n = 256*KP, stride = gridDim.x*256;
    for (int i = blockIdx.x*256 + threadIdx.x; i < n; i += stride) {
        int r = i / KP, k = i - r*KP;
        float v = 0.f;
        if (k < NMID) v = (r < NHID) ? wx[(size_t)r*NMID+k] : wy[(size_t)(r-NHID)*NMID+k];
        d[i] = f2bf(v);
    }
    for (int i = blockIdx.x*256 + threadIdx.x; i < 256; i += stride)
        hbias[i] = (i < NHID) ? b1[i] : 0.f;
}

// w_ih (4096 x 517) -> interleaved row u*4+g, padded to KP, bf16
__global__ __launch_bounds__(256) void prep_wih(const float* __restrict__ w,
                                                unsigned short* __restrict__ d)
{
    int n = 4*NOUT*KP, stride = gridDim.x*256;
    for (int i = blockIdx.x*256 + threadIdx.x; i < n; i += stride) {
        int row = i / KP, k = i - row*KP;
        int u = row >> 2, g = row & 3;
        d[i] = (k < NMID) ? f2bf(w[(size_t)(g*NOUT+u)*NMID + k]) : (unsigned short)0;
    }
}

// w_hh (4096 x 1024) -> interleaved row u*4+g, bf16
__global__ __launch_bounds__(256) void prep_whh(const float* __restrict__ w,
                                                unsigned short* __restrict__ d)
{
    int n = 4*NOUT*NOUT, stride = gridDim.x*256;
    for (int i = blockIdx.x*256 + threadIdx.x; i < n; i += stride) {
        int row = i >> 10, k = i & 1023;
        int u = row >> 2, g = row & 3;
        d[i] = f2bf(w[(size_t)(g*NOUT+u)*NOUT + k]);
    }
}

// combined interleaved bias (b_ih+b_hh), zero h0 (bf16) and c (fp32)
__global__ __launch_bounds__(256) void prep_misc(const float* __restrict__ b_ih,
                                                 const float* __restrict__ b_hh,
                                                 float* __restrict__ comb,
                                                 unsigned short* __restrict__ h0,
                                                 float* __restrict__ c)
{
    int stride = gridDim.x*256;
    for (int i = blockIdx.x*256 + threadIdx.x; i < 4*NOUT; i += stride) {
        int u = i >> 2, g = i & 3;
        comb[i] = b_ih[g*NOUT+u] + b_hh[g*NOUT+u];
    }
    for (int i = blockIdx.x*256 + threadIdx.x; i < NB*NOUT; i += stride) {
        h0[i] = 0; c[i] = 0.f;
    }
}

// ---------------------------------------------------------------------------
// bf16 MFMA GEMM: C[m,n] = sum_k A[m,k]*B[n,k] + bias[n]
// Block tile 128x64, 256 thr = 4 waves (2x2), wave tile 64x32.
// ---------------------------------------------------------------------------
__global__ __launch_bounds__(256) void gemm_mfma(
    const unsigned short* __restrict__ A, const unsigned short* __restrict__ B,
    const float* __restrict__ bias, void* __restrict__ Cp,
    int K, int lda, int ldb, int ldc, int obf)
{
    __shared__ __align__(16) char As[8192];   // 8 mtiles x 1KB
    __shared__ __align__(16) char Bs[4096];   // 4 ntiles x 1KB
    int m0 = blockIdx.y * 128, n0 = blockIdx.x * 64;
    int tid = threadIdx.x;
    int lane = tid & 63, wave = tid >> 6;
    int wm = wave >> 1, wn = wave & 1;
    f32x4 acc[4][2];
    #pragma unroll
    for (int i = 0; i < 4; ++i)
        #pragma unroll
        for (int j = 0; j < 2; ++j) acc[i][j] = (f32x4){0.f,0.f,0.f,0.f};

    for (int k0 = 0; k0 < K; k0 += 32) {
        #pragma unroll
        for (int cc = tid; cc < 512; cc += 256) {      // A: 128 rows x 4 quads
            int r = cc >> 2, q = cc & 3;
            uint4 v = *(const uint4*)(A + (size_t)(m0+r)*lda + k0 + q*8);
            *(uint4*)(As + ((r>>4)<<10) + (q<<8) + ((r&15)<<4)) = v;
        }
        {                                              // B: 64 rows x 4 quads
            int r = tid >> 2, q = tid & 3;
            uint4 v = *(const uint4*)(B + (size_t)(n0+r)*ldb + k0 + q*8);
            *(uint4*)(Bs + ((r>>4)<<10) + (q<<8) + ((r&15)<<4)) = v;
        }
        __syncthreads();
        bf16x8 af[4], bfr[2];
        #pragma unroll
        for (int i = 0; i < 4; ++i) af[i]  = *(bf16x8*)(As + ((wm*4+i)<<10) + (lane<<4));
        #pragma unroll
        for (int j = 0; j < 2; ++j) bfr[j] = *(bf16x8*)(Bs + ((wn*2+j)<<10) + (lane<<4));
        #pragma unroll
        for (int i = 0; i < 4; ++i)
            #pragma unroll
            for (int j = 0; j < 2; ++j)
                acc[i][j] = __builtin_amdgcn_mfma_f32_16x16x32_bf16(af[i], bfr[j], acc[i][j], 0, 0, 0);
        __syncthreads();
    }
    int colf = lane & 15, rowq = lane >> 4;
    #pragma unroll
    for (int j = 0; j < 2; ++j) {
        int col = n0 + (wn*2+j)*16 + colf;
        float bv = bias ? bias[col] : 0.f;
        #pragma unroll
        for (int i = 0; i < 4; ++i) {
            #pragma unroll
            for (int reg = 0; reg < 4; ++reg) {
                int row = m0 + (wm*4+i)*16 + rowq*4 + reg;
                float v = acc[i][j][reg] + bv;
                if (obf) ((unsigned short*)Cp)[(size_t)row*ldc + col] = f2bf(v);
                else     ((float*)Cp)[(size_t)row*ldc + col] = v;
            }
        }
    }
}

// ---------------------------------------------------------------------------
// per-batch: out = w2.relu(hx_i+hy_j), 3 assignment iters, final A row-softmax
// pre-scaled by sigmoid(att), xseq = A.feats (bf16, padded).
// LDS strides padded: hx/hy 129, 36x36 arrays 37 -> conflict-free.
// ---------------------------------------------------------------------------
__global__ __launch_bounds__(256) void assign_x(
    const float* __restrict__ feats, const float* __restrict__ hxy,
    const float* __restrict__ att, const float* __restrict__ w2,
    const float* __restrict__ lr, unsigned short* __restrict__ xseq)
{
    __shared__ float s_hx[NN*129], s_hy[NN*129];
    __shared__ float s_out[NN*S36], s_C[NN*S36], s_logits[NN*S36], s_P[NN*S36];
    __shared__ float s_sg[NN], s_w2[NHID];
    int b = blockIdx.x, tid = threadIdx.x;
    for (int i = tid; i < NN*NHID; i += 256) {
        int n = i >> 7, h = i & 127;
        s_hx[n*129+h] = hxy[(size_t)(b*NN+n)*256 + h];
        s_hy[n*129+h] = hxy[(size_t)(b*NN+n)*256 + 128 + h];
    }
    if (tid < NHID) s_w2[tid] = w2[tid];
    if (tid < NN)   s_sg[tid] = sigf(att[b*NN + tid]);
    float lr_abs = fabsf(lr[0]);
    __syncthreads();
    for (int idx = tid; idx < NN*NN; idx += 256) {
        int i = idx / NN, j = idx - i*NN;
        const float* px = &s_hx[i*129];
        const float* py = &s_hy[j*129];
        float s = 0.f;
        #pragma unroll 8
        for (int h = 0; h < NHID; ++h) s += s_w2[h] * fmaxf(px[h] + py[h], 0.f);
        s_out[i*S36+j] = s;
        s_logits[i*S36+j] = 0.f;
    }
    __syncthreads();
    for (int idx = tid; idx < NN*NN; idx += 256) {
        int i = idx / NN, j = idx - i*NN;
        s_C[i*S36+j] = s_out[i*S36+j] - s_out[j*S36+i];
    }
    __syncthreads();
    for (int it = 0; it < 3; ++it) {
        if (tid < NN) {
            int i = tid;
            float mx = -1e30f;
            for (int l = 0; l < NN; ++l) mx = fmaxf(mx, s_logits[i*S36+l]);
            float sum = 0.f;
            for (int l = 0; l < NN; ++l) { float e = expf(s_logits[i*S36+l]-mx); s_P[i*S36+l] = e; sum += e; }
            float inv = 1.f/sum;
            for (int l = 0; l < NN; ++l) s_P[i*S36+l] *= inv;
        }
        __syncthreads();
        if (tid < NN) {
            int l = tid;
            float S = 0.f;
            for (int i = 0; i < NN; ++i) S += s_P[i*S36+l];
            float cum = 0.f;
            for (int i = 0; i < NN; ++i) {
                float p = s_P[i*S36+l];
                cum += p;
                s_P[i*S36+l] = S - 2.f*cum + p;
            }
        }
        __syncthreads();
        for (int idx = tid; idx < NN*NN; idx += 256) {
            int i = idx / NN, j = idx - i*NN;
            float g = 0.f;
            #pragma unroll
            for (int l = 0; l < NN; ++l) g += s_P[i*S36+l] * s_C[j*S36+l];
            s_logits[i*S36+j] -= lr_abs * g;
        }
        __syncthreads();
    }
    if (tid < NN) {
        int i = tid;
        float mx = -1e30f;
        for (int l = 0; l < NN; ++l) mx = fmaxf(mx, s_logits[i*S36+l]);
        float sum = 0.f;
        for (int l = 0; l < NN; ++l) { float e = expf(s_logits[i*S36+l]-mx); s_P[i*S36+l] = e; sum += e; }
        float inv = 1.f/sum;
        for (int l = 0; l < NN; ++l) s_P[i*S36+l] *= inv * s_sg[l];
    }
    __syncthreads();
    // xseq[i][b][c] = sum_l A[i][l] * feats[b][l][c]; per-thread column regs
    const float* fb = feats + (size_t)b*NN*NMID;
    #pragma unroll
    for (int rep = 0; rep < 3; ++rep) {
        int c = rep*256 + tid;
        if (c < KP) {
            float colv[NN];
            #pragma unroll
            for (int l = 0; l < NN; ++l) colv[l] = (c < NMID) ? fb[l*NMID + c] : 0.f;
            #pragma unroll 4
            for (int i = 0; i < NN; ++i) {
                float s = 0.f;
                #pragma unroll
                for (int l = 0; l < NN; ++l) s += s_P[i*S36+l] * colv[l];
                xseq[((size_t)i*NB + b)*KP + c] = f2bf(s);
            }
        }
    }
}

// ---------------------------------------------------------------------------
// LSTM step, MFMA: tile 64 batch x 32 gate-cols, grid (128, 2) = 256 blocks.
// gates = h(bf16) . whh_il^T + xw (bf16, bias folded); c fp32 in-place,
// h_out bf16. Columns unit-interleaved: col = u*4+g.
// ---------------------------------------------------------------------------
__global__ __launch_bounds__(256) void lstm_step(
    const unsigned short* __restrict__ h_in, const unsigned short* __restrict__ whh,
    const unsigned short* __restrict__ xw_t, float* __restrict__ c,
    unsigned short* __restrict__ h_out)
{
    __shared__ __align__(16) char As[4096];     // 4 mtiles x 1KB
    __shared__ __align__(16) char Bs[2048];     // 2 ntiles x 1KB
    __shared__ float gates[64][36];             // stride 36 floats (144B, 16B-mult)
    int tid = threadIdx.x;
    int lane = tid & 63, wave = tid >> 6;
    int n0 = blockIdx.x * 32, m0 = blockIdx.y * 64;
    f32x4 acc[2];
    acc[0] = (f32x4){0.f,0.f,0.f,0.f};
    acc[1] = (f32x4){0.f,0.f,0.f,0.f};

    for (int k0 = 0; k0 < NOUT; k0 += 32) {
        {   // A: 64 rows x 4 quads = 256 chunks
            int r = tid >> 2, q = tid & 3;
            uint4 v = *(const uint4*)(h_in + (size_t)(m0+r)*NOUT + k0 + q*8);
            *(uint4*)(As + ((r>>4)<<10) + (q<<8) + ((r&15)<<4)) = v;
        }
        if (tid < 128) {  // B: 32 rows x 4 quads = 128 chunks
            int r = tid >> 2, q = tid & 3;
            uint4 v = *(const uint4*)(whh + (size_t)(n0+r)*NOUT + k0 + q*8);
            *(uint4*)(Bs + ((r>>4)<<10) + (q<<8) + ((r&15)<<4)) = v;
        }
        __syncthreads();
        bf16x8 af, bfr[2];
        af = *(bf16x8*)(As + (wave<<10) + (lane<<4));
        bfr[0] = *(bf16x8*)(Bs + (lane<<4));
        bfr[1] = *(bf16x8*)(Bs + 1024 + (lane<<4));
        acc[0] = __builtin_amdgcn_mfma_f32_16x16x32_bf16(af, bfr[0], acc[0], 0, 0, 0);
        acc[1] = __builtin_amdgcn_mfma_f32_16x16x32_bf16(af, bfr[1], acc[1], 0, 0, 0);
        __syncthreads();
    }
    int colf = lane & 15, rowq = lane >> 4;
    #pragma unroll
    for (int j = 0; j < 2; ++j)
        #pragma unroll
        for (int reg = 0; reg < 4; ++reg)
            gates[wave*16 + rowq*4 + reg][j*16 + colf] = acc[j][reg];
    __syncthreads();
    #pragma unroll
    for (int p = 0; p < 2; ++p) {
        int idx = p*256 + tid;       // 512 = 64 batches x 8 units
        int ul = idx & 7, bb = idx >> 3;
        float4 gl = *(const float4*)&gates[bb][ul*4];
        int b = m0 + bb;
        const unsigned short* xr = xw_t + (size_t)b*4*NOUT + n0 + ul*4;
        float g0 = gl.x + bf2f(xr[0]);
        float g1 = gl.y + bf2f(xr[1]);
        float g2 = gl.z + bf2f(xr[2]);
        float g3 = gl.w + bf2f(xr[3]);
        float ig = sigf(g0), fg = sigf(g1), gg = tanhf(g2), og = sigf(g3);
        size_t o = (size_t)b*NOUT + (n0>>2) + ul;
        float cc = fg*c[o] + ig*gg;
        c[o] = cc;
        h_out[o] = f2bf(og*tanhf(cc));
    }
}

__global__ __launch_bounds__(256) void copy_out(const float* __restrict__ c, float* __restrict__ out)
{
    int i = blockIdx.x*256 + threadIdx.x;
    out[i] = c[i];
}

// ---------------------------------------------------------------------------
extern "C" void kernel_launch(void* const* d_in, const int* in_sizes, int n_in,
                              void* d_out, int out_size, void* d_ws, size_t ws_size,
                              hipStream_t stream) {
    (void)in_sizes; (void)n_in; (void)out_size; (void)ws_size;
    const float* boxes     = (const float*)d_in[0];
    const float* attention = (const float*)d_in[1];
    const float* features  = (const float*)d_in[2];
    const float* conv_w    = (const float*)d_in[3];
    const float* conv_b    = (const float*)d_in[4];
    const float* skew_wx   = (const float*)d_in[5];
    const float* skew_wy   = (const float*)d_in[6];
    const float* skew_b1   = (const float*)d_in[7];
    const float* skew_w2   = (const float*)d_in[8];
    // d_in[9] = skew_b2: cancels in C = out - out^T
    const float* w_ih      = (const float*)d_in[10];
    const float* w_hh      = (const float*)d_in[11];
    const float* b_ih      = (const float*)d_in[12];
    const float* b_hh      = (const float*)d_in[13];
    const float* lr        = (const float*)d_in[14];

    // workspace layout (bytes, all 256-aligned)
    char* ws = (char*)d_ws;
    float*          feats    = (float*)(ws);                      // 4608x517 f32   9,529,344
    float*          hxy      = (float*)(ws + 9529344);            // 4608x256 f32   4,718,592
    unsigned short* feats_bf = (unsigned short*)(ws + 14247936);  // 4608x544 bf16  5,013,504
    unsigned short* xseq_bf  = (unsigned short*)(ws + 19261440);  // 4608x544 bf16  5,013,504
    unsigned short* wih_il   = (unsigned short*)(ws + 24274944);  // 4096x544 bf16  4,456,448
    unsigned short* whh_il   = (unsigned short*)(ws + 28731392);  // 4096x1024 bf16 8,388,608
    unsigned short* wxy_bf   = (unsigned short*)(ws + 37120000);  // 256x544 bf16     278,528
    float*          comb_b   = (float*)(ws + 37398528);           // 4096 f32          16,384
    float*          hxy_b    = (float*)(ws + 37414912);           // 256 f32            1,024
    unsigned short* h0       = (unsigned short*)(ws + 37416192);  // 128x1024 bf16    262,144
    unsigned short* h1       = (unsigned short*)(ws + 37678336);  // 128x1024 bf16    262,144
    float*          cst      = (float*)(ws + 37940480);           // 128x1024 f32     524,288
    unsigned short* xw_bf    = (unsigned short*)(ws + 38464768);  // 4608x4096 bf16 37,748,736
    // features_bf / convw_bf overlap xw_bf region (dead before xw GEMM writes)
    unsigned short* features_bf = xw_bf;                          // 4608x2048 bf16
    unsigned short* convw_bf = (unsigned short*)(ws + 38464768 + 18874368); // 512x2048 bf16

    // prep
    fill_small<<<NB, 64, 0, stream>>>(boxes, attention, feats);
    cast_bf16<<<2048, 256, 0, stream>>>(features, features_bf, ROWS*NFEAT);
    cast_bf16<<<512, 256, 0, stream>>>(conv_w, convw_bf, 512*NFEAT);
    prep_wih<<<1024, 256, 0, stream>>>(w_ih, wih_il);
    prep_whh<<<2048, 256, 0, stream>>>(w_hh, whh_il);
    prep_misc<<<512, 256, 0, stream>>>(b_ih, b_hh, comb_b, h0, cst);
    build_wxy<<<128, 256, 0, stream>>>(skew_wx, skew_wy, skew_b1, wxy_bf, hxy_b);

    // conv: feats[:,5:517] = features . conv_w^T + conv_b
    gemm_mfma<<<dim3(8, 36), 256, 0, stream>>>(features_bf, convw_bf, conv_b,
                                               (void*)(feats + 5), NFEAT, NFEAT, NFEAT, NMID, 0);
    cast_pad<<<1024, 256, 0, stream>>>(feats, feats_bf, ROWS, NMID);
    // hxy = feats . [wx;wy]^T + [b1;0]
    gemm_mfma<<<dim3(4, 36), 256, 0, stream>>>(feats_bf, wxy_bf, hxy_b,
                                               (void*)hxy, KP, KP, KP, 256, 0);
    assign_x<<<NB, 256, 0, stream>>>(feats, hxy, attention, skew_w2, lr, xseq_bf);
    // xw = xseq . w_ih_il^T + (b_ih+b_hh)  -> bf16
    gemm_mfma<<<dim3(64, 36), 256, 0, stream>>>(xseq_bf, wih_il, comb_b,
                                                (void*)xw_bf, KP, KP, KP, 4*NOUT, 1);
    unsigned short* hbuf[2] = {h0, h1};
    for (int t = 0; t < NN; ++t) {
        lstm_step<<<dim3(128, 2), 256, 0, stream>>>(hbuf[t & 1], whh_il,
                                                    xw_bf + (size_t)t*NB*4*NOUT, cst, hbuf[(t+1) & 1]);
    }
    copy_out<<<(NB*NOUT)/256, 256, 0, stream>>>(cst, (float*)d_out);
}